// Round 5
// baseline (583.172 us; speedup 1.0000x reference)
//
#include <hip/hip_runtime.h>
#include <hip/hip_bf16.h>

#define S 8192
#define D 128
#define G 1024
#define SHIFTC 512
#define SMASK 8191
// head_dim^-0.5 * log2(e): scores feed exp2 directly
#define SCALE_L2E 0.12751743232f
#define KVB 64
#define NTILE 16
#define QT 256

typedef __attribute__((ext_vector_type(8))) short short8;
typedef __attribute__((ext_vector_type(16))) float f32x16;

__device__ inline short f2bf(float f) {
    __hip_bfloat16 h = __float2bfloat16(f);
    return *(short*)&h;
}
__device__ inline int cvtpk(float lo, float hi) {
    int r;
    asm("v_cvt_pk_bf16_f32 %0, %1, %2" : "=v"(r) : "v"(lo), "v"(hi));
    return r;
}
__device__ inline float vcomp(const float4& v, int dd) {
    switch (dd) { case 0: return v.x; case 1: return v.y; case 2: return v.z; default: return v.w; }
}

__global__ __launch_bounds__(512, 4) void ssattn(
        const float* __restrict__ qg, const float* __restrict__ kg,
        const float* __restrict__ vg, float* __restrict__ og) {
    __shared__ ushort Klds[KVB * D];  // [64][128] bf16, XOR-swizzled
    __shared__ ushort Vt[D * KVB];    // [128][64] bf16 transposed, XOR-swizzled
    __shared__ float lbuf[8][32];     // per-wave row-sum broadcast

    const int bid = blockIdx.x;
    const int swz = (bid & 7) * 64 + (bid >> 3);  // XCD-bijective (512 % 8 == 0)
    const int head = swz >> 5;        // 32 blocks per head
    const int grp = (swz >> 2) & 7;   // 4 q-tile blocks per group
    const int qt = swz & 3;

    const int tid = threadIdx.x;
    const int w = tid >> 6;
    const int l = tid & 63;
    const int lq = l & 31;
    const int hi = l >> 5;

    const size_t hb = (size_t)head * S * D;
    const float* qph = qg + hb;
    const float* kph = kg + hb;
    const float* vph = vg + hb;
    float* oph = og + hb;

    const int kbase = grp * G;
    const int qr0 = grp * G + qt * QT + w * 32;

    // staging roles: waves 0-3 stage K, waves 4-7 stage V
    const bool wlow = (tid < 256);
    const int t2 = tid & 255;
    const int krow = t2 >> 4;        // 0..15
    const int kc0 = (t2 & 15) * 8;   // col oct (floats)
    const int vk0 = (t2 & 7) * 8;    // 8 keys per thread
    const int vd0 = (t2 >> 3) * 4;   // 4 d per thread

    float4 stg[8];  // K: [p][2] pairs; V: [8] — time-shared

    // ---- issue tile-0 loads
    if (wlow) {
#pragma unroll
        for (int p = 0; p < 4; ++p) {
            int r = (kbase + krow + p * 16 + SHIFTC) & SMASK;
            const float* sp = kph + (size_t)r * D + kc0;
            stg[2 * p] = *(const float4*)(sp);
            stg[2 * p + 1] = *(const float4*)(sp + 4);
        }
    } else {
#pragma unroll
        for (int m = 0; m < 8; ++m) {
            int r = (kbase + vk0 + m + SHIFTC) & SMASK;
            stg[m] = *(const float4*)(vph + (size_t)r * D + vd0);
        }
    }

    // ---- Q fragments: B-operand layout, lane holds Q[q=lq][d=16kk+8hi+j]
    short8 qf[8];
    {
        int qs = (qr0 + lq + SHIFTC) & SMASK;
        const float* qp = qph + (size_t)qs * D + hi * 8;
#pragma unroll
        for (int kk = 0; kk < 8; ++kk) {
            float4 a = *(const float4*)(qp + kk * 16);
            float4 b = *(const float4*)(qp + kk * 16 + 4);
            short8 f;
            f[0] = f2bf(a.x * SCALE_L2E); f[1] = f2bf(a.y * SCALE_L2E);
            f[2] = f2bf(a.z * SCALE_L2E); f[3] = f2bf(a.w * SCALE_L2E);
            f[4] = f2bf(b.x * SCALE_L2E); f[5] = f2bf(b.y * SCALE_L2E);
            f[6] = f2bf(b.z * SCALE_L2E); f[7] = f2bf(b.w * SCALE_L2E);
            qf[kk] = f;
        }
    }

    f32x16 o[4];
#pragma unroll
    for (int n = 0; n < 4; ++n)
#pragma unroll
        for (int i = 0; i < 16; ++i) o[n][i] = 0.f;
    float l_run = 0.f;

    for (int t = 0; t < NTILE; ++t) {
        __syncthreads();  // all waves done reading previous LDS tile

        if (wlow) {
            // ---- write K tile
#pragma unroll
            for (int p = 0; p < 4; ++p) {
                int row = krow + p * 16;
                short8 f;
                f[0] = f2bf(stg[2 * p].x); f[1] = f2bf(stg[2 * p].y);
                f[2] = f2bf(stg[2 * p].z); f[3] = f2bf(stg[2 * p].w);
                f[4] = f2bf(stg[2 * p + 1].x); f[5] = f2bf(stg[2 * p + 1].y);
                f[6] = f2bf(stg[2 * p + 1].z); f[7] = f2bf(stg[2 * p + 1].w);
                int e = (row * D + kc0) ^ ((row & 7) << 3);
                *(short8*)(&Klds[e]) = f;
            }
        } else {
            // ---- write V transposed (register transpose -> b128)
#pragma unroll
            for (int dd = 0; dd < 4; ++dd) {
                int d = vd0 + dd;
                short8 f;
#pragma unroll
                for (int m = 0; m < 8; ++m) f[m] = f2bf(vcomp(stg[m], dd));
                int e = (d * KVB + vk0) ^ ((d & 7) << 3);
                *(short8*)(&Vt[e]) = f;
            }
        }
        __syncthreads();  // staged tile visible

        // ---- prefetch next tile (overlaps QK+softmax+PV)
        if (t + 1 < NTILE) {
            int kb = kbase + (t + 1) * KVB;
            if (wlow) {
#pragma unroll
                for (int p = 0; p < 4; ++p) {
                    int r = (kb + krow + p * 16 + SHIFTC) & SMASK;
                    const float* sp = kph + (size_t)r * D + kc0;
                    stg[2 * p] = *(const float4*)(sp);
                    stg[2 * p + 1] = *(const float4*)(sp + 4);
                }
            } else {
#pragma unroll
                for (int m = 0; m < 8; ++m) {
                    int r = (kb + vk0 + m + SHIFTC) & SMASK;
                    stg[m] = *(const float4*)(vph + (size_t)r * D + vd0);
                }
            }
        }

        // ---- QK^T swapped: st[kr] = K(32 rows) . Q^T -> lane: q=lq, k=crow(r,hi)
        f32x16 st[2];
#pragma unroll
        for (int kr = 0; kr < 2; ++kr)
#pragma unroll
            for (int i = 0; i < 16; ++i) st[kr][i] = 0.f;
        __builtin_amdgcn_s_setprio(1);
#pragma unroll
        for (int kk = 0; kk < 8; ++kk) {
#pragma unroll
            for (int kr = 0; kr < 2; ++kr) {
                int row = kr * 32 + lq;
                int e = (row * D + kk * 16 + hi * 8) ^ ((row & 7) << 3);
                short8 kf = *(const short8*)(&Klds[e]);
                st[kr] = __builtin_amdgcn_mfma_f32_32x32x16_bf16(kf, qf[kk], st[kr], 0, 0, 0);
            }
        }
        __builtin_amdgcn_s_setprio(0);

        // ---- softmax: scores pre-scaled by log2(e) -> exp2 direct; tree sum
        float ts0 = 0.f, ts1 = 0.f, ts2 = 0.f, ts3 = 0.f;
#pragma unroll
        for (int kr = 0; kr < 2; ++kr) {
#pragma unroll
            for (int r = 0; r < 16; r += 4) {
                float e0 = __builtin_amdgcn_exp2f(st[kr][r + 0]);
                float e1 = __builtin_amdgcn_exp2f(st[kr][r + 1]);
                float e2 = __builtin_amdgcn_exp2f(st[kr][r + 2]);
                float e3 = __builtin_amdgcn_exp2f(st[kr][r + 3]);
                st[kr][r + 0] = e0; st[kr][r + 1] = e1;
                st[kr][r + 2] = e2; st[kr][r + 3] = e3;
                ts0 += e0; ts1 += e1; ts2 += e2; ts3 += e3;
            }
        }
        float ts = (ts0 + ts1) + (ts2 + ts3);
        ts += __shfl_xor(ts, 32);
        l_run += ts;

        // ---- P -> PV A-frags in-register: cvt_pk + permlane32_swap
        // HW: v_permlane32_swap_b32 vdst,vsrc => vdst=[vdst.lo|vsrc.lo], vsrc=[vdst.hi|vsrc.hi]
        short8 pa[4];
#pragma unroll
        for (int ks = 0; ks < 4; ++ks) {
            int base = 8 * (ks & 1);
            int kr = ks >> 1;
            int w0, w1, w2, w3;
            {
                int a = cvtpk(st[kr][base + 0], st[kr][base + 1]);
                int b = cvtpk(st[kr][base + 4], st[kr][base + 5]);
                asm volatile("v_permlane32_swap_b32 %0, %1" : "+v"(a), "+v"(b));
                w0 = a; w2 = b;
            }
            {
                int a = cvtpk(st[kr][base + 2], st[kr][base + 3]);
                int b = cvtpk(st[kr][base + 6], st[kr][base + 7]);
                asm volatile("v_permlane32_swap_b32 %0, %1" : "+v"(a), "+v"(b));
                w1 = a; w3 = b;
            }
            int4 wi = make_int4(w0, w1, w2, w3);
            pa[ks] = *(short8*)(&wi);
        }

        // ---- PV: o[n] += P . V(:, 32n..32n+31)
        __builtin_amdgcn_s_setprio(1);
#pragma unroll
        for (int n = 0; n < 4; ++n) {
#pragma unroll
            for (int ks = 0; ks < 4; ++ks) {
                int d = 32 * n + lq;
                int e = (d * KVB + ks * 16 + hi * 8) ^ ((d & 7) << 3);
                short8 vf = *(const short8*)(&Vt[e]);
                o[n] = __builtin_amdgcn_mfma_f32_32x32x16_bf16(pa[ks], vf, o[n], 0, 0, 0);
            }
        }
        __builtin_amdgcn_s_setprio(0);
    }

    // ---- epilogue: broadcast 1/l via per-wave LDS, store
    if (hi == 0) lbuf[w][lq] = l_run;
    __builtin_amdgcn_s_barrier();
#pragma unroll
    for (int r = 0; r < 16; ++r) {
        int qv = (r & 3) + 8 * (r >> 2) + 4 * hi;
        float li = 1.f / lbuf[w][qv];
        int oseq = (qr0 + qv + SHIFTC) & SMASK;
        float* dst = oph + (size_t)oseq * D + lq;
#pragma unroll
        for (int n = 0; n < 4; ++n) dst[n * 32] = o[n][r] * li;
    }
}

extern "C" void kernel_launch(void* const* d_in, const int* in_sizes, int n_in,
                              void* d_out, int out_size, void* d_ws, size_t ws_size,
                              hipStream_t stream) {
    const float* q = (const float*)d_in[0];
    const float* k = (const float*)d_in[1];
    const float* v = (const float*)d_in[2];
    float* o = (float*)d_out;
    ssattn<<<dim3(512), dim3(512), 0, stream>>>(q, k, v, o);
}

// Round 6
// 251.018 us; speedup vs baseline: 2.3232x; 2.3232x over previous
//
#include <hip/hip_runtime.h>
#include <hip/hip_bf16.h>

#define S 8192
#define D 128
#define G 1024
#define SHIFTC 512
#define SMASK 8191
// head_dim^-0.5 * log2(e): scores feed exp2 directly
#define SCALE_L2E 0.12751743232f
#define KVB 64
#define NTILE 16
#define QT 256

typedef __attribute__((ext_vector_type(8))) short short8;
typedef __attribute__((ext_vector_type(16))) float f32x16;

__device__ inline short f2bf(float f) {
    __hip_bfloat16 h = __float2bfloat16(f);
    return *(short*)&h;
}
__device__ inline int cvtpk(float lo, float hi) {
    int r;
    asm("v_cvt_pk_bf16_f32 %0, %1, %2" : "=v"(r) : "v"(lo), "v"(hi));
    return r;
}
__device__ inline float vcomp(const float4& v, int dd) {
    switch (dd) { case 0: return v.x; case 1: return v.y; case 2: return v.z; default: return v.w; }
}

__global__ __launch_bounds__(512, 2) void ssattn(
        const float* __restrict__ qg, const float* __restrict__ kg,
        const float* __restrict__ vg, float* __restrict__ og) {
    __shared__ ushort Klds[KVB * D];  // [64][128] bf16, XOR-swizzled
    __shared__ ushort Vt[D * KVB];    // [128][64] bf16 transposed, XOR-swizzled
    __shared__ float lbuf[8][32];     // per-wave row-sum broadcast

    const int bid = blockIdx.x;
    const int swz = (bid & 7) * 64 + (bid >> 3);  // XCD-bijective (512 % 8 == 0)
    const int head = swz >> 5;        // 32 blocks per head
    const int grp = (swz >> 2) & 7;   // 4 q-tile blocks per group
    const int qt = swz & 3;

    const int tid = threadIdx.x;
    const int w = tid >> 6;
    const int l = tid & 63;
    const int lq = l & 31;
    const int hi = l >> 5;

    const size_t hb = (size_t)head * S * D;
    const float* qph = qg + hb;
    const float* kph = kg + hb;
    const float* vph = vg + hb;
    float* oph = og + hb;

    const int kbase = grp * G;
    const int qr0 = grp * G + qt * QT + w * 32;

    // staging roles: waves 0-3 stage K, waves 4-7 stage V
    const bool wlow = (tid < 256);
    const int t2 = tid & 255;
    const int krow = t2 >> 4;        // 0..15
    const int kc0 = (t2 & 15) * 8;   // col oct (floats)
    const int vk0 = (t2 & 7) * 8;    // 8 keys per thread
    const int vd0 = (t2 >> 3) * 4;   // 4 d per thread

    float4 stg[8];  // K: [p][2] pairs; V: [8] — time-shared

    // ---- issue tile-0 loads
    if (wlow) {
#pragma unroll
        for (int p = 0; p < 4; ++p) {
            int r = (kbase + krow + p * 16 + SHIFTC) & SMASK;
            const float* sp = kph + (size_t)r * D + kc0;
            stg[2 * p] = *(const float4*)(sp);
            stg[2 * p + 1] = *(const float4*)(sp + 4);
        }
    } else {
#pragma unroll
        for (int m = 0; m < 8; ++m) {
            int r = (kbase + vk0 + m + SHIFTC) & SMASK;
            stg[m] = *(const float4*)(vph + (size_t)r * D + vd0);
        }
    }

    // ---- Q fragments: B-operand layout, lane holds Q[q=lq][d=16kk+8hi+j]
    short8 qf[8];
    {
        int qs = (qr0 + lq + SHIFTC) & SMASK;
        const float* qp = qph + (size_t)qs * D + hi * 8;
#pragma unroll
        for (int kk = 0; kk < 8; ++kk) {
            float4 a = *(const float4*)(qp + kk * 16);
            float4 b = *(const float4*)(qp + kk * 16 + 4);
            short8 f;
            f[0] = f2bf(a.x * SCALE_L2E); f[1] = f2bf(a.y * SCALE_L2E);
            f[2] = f2bf(a.z * SCALE_L2E); f[3] = f2bf(a.w * SCALE_L2E);
            f[4] = f2bf(b.x * SCALE_L2E); f[5] = f2bf(b.y * SCALE_L2E);
            f[6] = f2bf(b.z * SCALE_L2E); f[7] = f2bf(b.w * SCALE_L2E);
            qf[kk] = f;
        }
    }

    f32x16 o[4];
#pragma unroll
    for (int n = 0; n < 4; ++n)
#pragma unroll
        for (int i = 0; i < 16; ++i) o[n][i] = 0.f;
    float l_run = 0.f;

    for (int t = 0; t < NTILE; ++t) {
        __syncthreads();  // all waves done reading previous LDS tile

        if (wlow) {
            // ---- write K tile
#pragma unroll
            for (int p = 0; p < 4; ++p) {
                int row = krow + p * 16;
                short8 f;
                f[0] = f2bf(stg[2 * p].x); f[1] = f2bf(stg[2 * p].y);
                f[2] = f2bf(stg[2 * p].z); f[3] = f2bf(stg[2 * p].w);
                f[4] = f2bf(stg[2 * p + 1].x); f[5] = f2bf(stg[2 * p + 1].y);
                f[6] = f2bf(stg[2 * p + 1].z); f[7] = f2bf(stg[2 * p + 1].w);
                int e = (row * D + kc0) ^ ((row & 7) << 3);
                *(short8*)(&Klds[e]) = f;
            }
        } else {
            // ---- write V transposed (register transpose -> b128)
#pragma unroll
            for (int dd = 0; dd < 4; ++dd) {
                int d = vd0 + dd;
                short8 f;
#pragma unroll
                for (int m = 0; m < 8; ++m) f[m] = f2bf(vcomp(stg[m], dd));
                int e = (d * KVB + vk0) ^ ((d & 7) << 3);
                *(short8*)(&Vt[e]) = f;
            }
        }
        __syncthreads();  // staged tile visible

        // ---- prefetch next tile (overlaps QK+softmax+PV)
        if (t + 1 < NTILE) {
            int kb = kbase + (t + 1) * KVB;
            if (wlow) {
#pragma unroll
                for (int p = 0; p < 4; ++p) {
                    int r = (kb + krow + p * 16 + SHIFTC) & SMASK;
                    const float* sp = kph + (size_t)r * D + kc0;
                    stg[2 * p] = *(const float4*)(sp);
                    stg[2 * p + 1] = *(const float4*)(sp + 4);
                }
            } else {
#pragma unroll
                for (int m = 0; m < 8; ++m) {
                    int r = (kb + vk0 + m + SHIFTC) & SMASK;
                    stg[m] = *(const float4*)(vph + (size_t)r * D + vd0);
                }
            }
        }

        // ---- QK^T swapped: st[kr] = K(32 rows) . Q^T -> lane: q=lq, k=crow(r,hi)
        f32x16 st[2];
#pragma unroll
        for (int kr = 0; kr < 2; ++kr)
#pragma unroll
            for (int i = 0; i < 16; ++i) st[kr][i] = 0.f;
        __builtin_amdgcn_s_setprio(1);
#pragma unroll
        for (int kk = 0; kk < 8; ++kk) {
#pragma unroll
            for (int kr = 0; kr < 2; ++kr) {
                int row = kr * 32 + lq;
                int e = (row * D + kk * 16 + hi * 8) ^ ((row & 7) << 3);
                short8 kf = *(const short8*)(&Klds[e]);
                st[kr] = __builtin_amdgcn_mfma_f32_32x32x16_bf16(kf, qf[kk], st[kr], 0, 0, 0);
            }
        }
        __builtin_amdgcn_s_setprio(0);

        // ---- softmax: scores pre-scaled by log2(e) -> exp2 direct; tree sum
        float ts0 = 0.f, ts1 = 0.f, ts2 = 0.f, ts3 = 0.f;
#pragma unroll
        for (int kr = 0; kr < 2; ++kr) {
#pragma unroll
            for (int r = 0; r < 16; r += 4) {
                float e0 = __builtin_amdgcn_exp2f(st[kr][r + 0]);
                float e1 = __builtin_amdgcn_exp2f(st[kr][r + 1]);
                float e2 = __builtin_amdgcn_exp2f(st[kr][r + 2]);
                float e3 = __builtin_amdgcn_exp2f(st[kr][r + 3]);
                st[kr][r + 0] = e0; st[kr][r + 1] = e1;
                st[kr][r + 2] = e2; st[kr][r + 3] = e3;
                ts0 += e0; ts1 += e1; ts2 += e2; ts3 += e3;
            }
        }
        float ts = (ts0 + ts1) + (ts2 + ts3);
        ts += __shfl_xor(ts, 32);
        l_run += ts;

        // ---- P -> PV A-frags in-register: cvt_pk + permlane32_swap
        // HW: v_permlane32_swap_b32 vdst,vsrc => vdst=[vdst.lo|vsrc.lo], vsrc=[vdst.hi|vsrc.hi]
        short8 pa[4];
#pragma unroll
        for (int ks = 0; ks < 4; ++ks) {
            int base = 8 * (ks & 1);
            int kr = ks >> 1;
            int w0, w1, w2, w3;
            {
                int a = cvtpk(st[kr][base + 0], st[kr][base + 1]);
                int b = cvtpk(st[kr][base + 4], st[kr][base + 5]);
                asm volatile("v_permlane32_swap_b32 %0, %1" : "+v"(a), "+v"(b));
                w0 = a; w2 = b;
            }
            {
                int a = cvtpk(st[kr][base + 2], st[kr][base + 3]);
                int b = cvtpk(st[kr][base + 6], st[kr][base + 7]);
                asm volatile("v_permlane32_swap_b32 %0, %1" : "+v"(a), "+v"(b));
                w1 = a; w3 = b;
            }
            int4 wi = make_int4(w0, w1, w2, w3);
            pa[ks] = *(short8*)(&wi);
        }

        // ---- PV: o[n] += P . V(:, 32n..32n+31)
        __builtin_amdgcn_s_setprio(1);
#pragma unroll
        for (int n = 0; n < 4; ++n) {
#pragma unroll
            for (int ks = 0; ks < 4; ++ks) {
                int d = 32 * n + lq;
                int e = (d * KVB + ks * 16 + hi * 8) ^ ((d & 7) << 3);
                short8 vf = *(const short8*)(&Vt[e]);
                o[n] = __builtin_amdgcn_mfma_f32_32x32x16_bf16(pa[ks], vf, o[n], 0, 0, 0);
            }
        }
        __builtin_amdgcn_s_setprio(0);
    }

    // ---- epilogue: broadcast 1/l via per-wave LDS, store
    if (hi == 0) lbuf[w][lq] = l_run;
    __builtin_amdgcn_s_barrier();
#pragma unroll
    for (int r = 0; r < 16; ++r) {
        int qv = (r & 3) + 8 * (r >> 2) + 4 * hi;
        float li = 1.f / lbuf[w][qv];
        int oseq = (qr0 + qv + SHIFTC) & SMASK;
        float* dst = oph + (size_t)oseq * D + lq;
#pragma unroll
        for (int n = 0; n < 4; ++n) dst[n * 32] = o[n][r] * li;
    }
}

extern "C" void kernel_launch(void* const* d_in, const int* in_sizes, int n_in,
                              void* d_out, int out_size, void* d_ws, size_t ws_size,
                              hipStream_t stream) {
    const float* q = (const float*)d_in[0];
    const float* k = (const float*)d_in[1];
    const float* v = (const float*)d_in[2];
    float* o = (float*)d_out;
    ssattn<<<dim3(512), dim3(512), 0, stream>>>(q, k, v, o);
}